// Round 2
// baseline (307.951 us; speedup 1.0000x reference)
//
#include <hip/hip_runtime.h>

#define B_   8
#define T_   4096
#define D_   1024
#define E_   100
#define EP_  128
#define NTOK (B_*T_)

typedef short bf16x8 __attribute__((ext_vector_type(8)));
typedef float f32x4  __attribute__((ext_vector_type(4)));

__device__ __forceinline__ float b2f(unsigned int u){
    union { unsigned int i; float f; } v; v.i = u << 16; return v.f;
}
__device__ __forceinline__ unsigned short f2b(float f){
    union { float f; unsigned int i; } v; v.f = f;
    unsigned int x = v.i;
    return (unsigned short)((x + 0x7fffu + ((x >> 16) & 1u)) >> 16);
}

// ---------------- K1: normalize centroids (fp32 in) -> cn[EP_][D_] bf16 --------
__global__ __launch_bounds__(256) void k_cnorm(const float* __restrict__ cent,
                                               unsigned short* __restrict__ cn){
    const int e = blockIdx.x, tid = threadIdx.x;
    if (e >= E_){
        ((uint2*)(cn + (size_t)e*D_))[tid] = make_uint2(0u, 0u);
        return;
    }
    float4 x = ((const float4*)(cent + (size_t)e*D_))[tid];
    float ss = x.x*x.x + x.y*x.y + x.z*x.z + x.w*x.w;
    __shared__ float red[256];
    red[tid] = ss; __syncthreads();
    for (int s = 128; s > 0; s >>= 1){ if (tid < s) red[tid] += red[tid+s]; __syncthreads(); }
    float inv = 1.0f / fmaxf(sqrtf(red[0]), 1e-12f);
    unsigned int lo = (unsigned int)f2b(x.x*inv) | ((unsigned int)f2b(x.y*inv) << 16);
    unsigned int hi = (unsigned int)f2b(x.z*inv) | ((unsigned int)f2b(x.w*inv) << 16);
    ((uint2*)(cn + (size_t)e*D_))[tid] = make_uint2(lo, hi);
}

// ---------------- K2: sim GEMM (fused token norm) + softmax -------------------
// grid = NTOK/128 blocks, 256 threads. Tile: 128 tokens x 128 entities, K=1024.
__global__ __launch_bounds__(256) void k_sim(const float* __restrict__ tokens,
                                             const unsigned short* __restrict__ cn,
                                             float* __restrict__ out_assign,
                                             unsigned short* __restrict__ pT){
    const int tid = threadIdx.x;
    const int t0  = blockIdx.x * 128;

    __shared__ __align__(16) unsigned char smem[128*133*4];   // union: A/B tiles | sim
    unsigned short* lds_a = (unsigned short*)smem;            // [128][72] bf16
    unsigned short* lds_b = lds_a + 128*72;                   // [128][72] bf16
    float* lds_sim = (float*)smem;                            // [128][133] f32
    __shared__ float red[256];
    __shared__ float srow[128];
    __shared__ float rowm[128];
    __shared__ float rowr[128];

    const int r = tid >> 1, seg = tid & 1;
    const float*          gA = tokens + (size_t)(t0 + r)*D_ + seg*32;
    const unsigned short* gB = cn     + (size_t)r*D_        + seg*32;
    unsigned short* sA = lds_a + r*72 + seg*32;
    unsigned short* sB = lds_b + r*72 + seg*32;

    const int lane = tid & 63, w = tid >> 6;
    const int wm = w >> 1, wn = w & 1, lrow = lane & 15, quad = lane >> 4;

    f32x4 acc[4][4];
    #pragma unroll
    for (int i = 0; i < 4; i++)
        #pragma unroll
        for (int j = 0; j < 4; j++) acc[i][j] = (f32x4){0.f,0.f,0.f,0.f};

    float ss = 0.f;

    for (int ki = 0; ki < 16; ki++){
        const int k0 = ki * 64;
        // A: 32 fp32 per thread -> bf16 into LDS; accumulate fp32 sum-of-squares
        #pragma unroll
        for (int j = 0; j < 8; j++){
            float4 ra = *(const float4*)(gA + k0 + j*4);
            ss += ra.x*ra.x + ra.y*ra.y + ra.z*ra.z + ra.w*ra.w;
            unsigned int lo = (unsigned int)f2b(ra.x) | ((unsigned int)f2b(ra.y) << 16);
            unsigned int hi = (unsigned int)f2b(ra.z) | ((unsigned int)f2b(ra.w) << 16);
            *(uint2*)(sA + j*4) = make_uint2(lo, hi);
        }
        // B: 32 bf16 per thread (already bf16 in ws)
        #pragma unroll
        for (int j = 0; j < 4; j++){
            uint4 rb = *(const uint4*)(gB + k0 + j*8);
            *(uint4*)(sB + j*8) = rb;
        }
        __syncthreads();
        #pragma unroll
        for (int kk = 0; kk < 64; kk += 32){
            bf16x8 af[4], bfr[4];
            #pragma unroll
            for (int mi = 0; mi < 4; mi++)
                af[mi] = *(const bf16x8*)(lds_a + (wm*64 + mi*16 + lrow)*72 + kk + quad*8);
            #pragma unroll
            for (int ni = 0; ni < 4; ni++)
                bfr[ni] = *(const bf16x8*)(lds_b + (wn*64 + ni*16 + lrow)*72 + kk + quad*8);
            #pragma unroll
            for (int mi = 0; mi < 4; mi++)
                #pragma unroll
                for (int ni = 0; ni < 4; ni++)
                    acc[mi][ni] = __builtin_amdgcn_mfma_f32_16x16x32_bf16(af[mi], bfr[ni], acc[mi][ni], 0, 0, 0);
        }
        __syncthreads();
    }

    // fused token norms: 2 partials per row
    red[tid] = ss; __syncthreads();
    if (tid < 128){
        float tot = red[2*tid] + red[2*tid+1];
        srow[tid] = 10.0f / fmaxf(sqrtf(tot), 1e-12f);   // 1/(max(norm,eps)*TEMP)
    }
    __syncthreads();

    // write scaled sim into union region (A/B tiles dead now)
    #pragma unroll
    for (int mi = 0; mi < 4; mi++){
        int row = wm*64 + mi*16 + quad*4;
        #pragma unroll
        for (int ni = 0; ni < 4; ni++){
            int col = wn*64 + ni*16 + lrow;
            #pragma unroll
            for (int rr = 0; rr < 4; rr++)
                lds_sim[(row+rr)*133 + col] = acc[mi][ni][rr] * srow[row+rr];
        }
    }
    __syncthreads();

    if (tid < 128){
        float m = -1e30f;
        for (int e = 0; e < E_; e++) m = fmaxf(m, lds_sim[tid*133 + e]);
        float s = 0.f;
        for (int e = 0; e < E_; e++) s += __expf(lds_sim[tid*133 + e] - m);
        rowm[tid] = m; rowr[tid] = 1.0f / s;
    }
    __syncthreads();

    const int bb    = t0 >> 12;        // batch index (128 | 4096)
    const int tloc0 = t0 & (T_ - 1);
    for (int i = tid; i < 128*E_; i += 256){
        int t = i / 100, e = i - t*100;
        float p = __expf(lds_sim[t*133 + e] - rowm[t]) * rowr[t];
        out_assign[(size_t)(t0 + t)*E_ + e] = p;
        pT[((size_t)bb*EP_ + e)*T_ + tloc0 + t] = f2b(p);
    }
    // zero the padded entity rows of pT for this token range
    for (int i = tid; i < 128*(EP_ - E_); i += 256){
        int e = E_ + (i >> 7), t = i & 127;
        pT[((size_t)bb*EP_ + e)*T_ + tloc0 + t] = 0;
    }
}

// ---------------- K3: entity_features = p^T x / (w+eps) ------------------------
// grid = (32 d-tiles, 8 batches), 256 threads. Tile: 128 e x 32 d, K=T.
__global__ __launch_bounds__(256) void k_feat(const float* __restrict__ tokens,
                                              const unsigned short* __restrict__ pT,
                                              float* __restrict__ out_feat){
    const int tid = threadIdx.x;
    const int d0  = blockIdx.x * 32;
    const int by  = blockIdx.y;

    __shared__ __align__(16) unsigned short lds_a[128*72];   // [e][kt] bf16
    __shared__ __align__(16) unsigned short lds_bt[32*72];   // [d][kt] bf16 (transposed x)
    __shared__ float red[256];
    __shared__ float winv[128];

    const int er = tid >> 1, seg = tid & 1;
    const unsigned short* gA = pT + ((size_t)by*EP_ + er)*T_ + seg*32;
    unsigned short* sA = lds_a + er*72 + seg*32;

    const int ktr = tid >> 2, dseg = tid & 3;
    const float* gB = tokens + ((size_t)by*T_ + ktr)*D_ + d0 + dseg*8;

    const int lane = tid & 63, w = tid >> 6, lrow = lane & 15, quad = lane >> 4;

    f32x4 acc[2][2];
    #pragma unroll
    for (int i = 0; i < 2; i++)
        #pragma unroll
        for (int j = 0; j < 2; j++) acc[i][j] = (f32x4){0.f,0.f,0.f,0.f};
    float sp = 0.f;

    for (int kt0 = 0; kt0 < T_; kt0 += 64){
        #pragma unroll
        for (int j = 0; j < 4; j++){
            uint4 ra = *(const uint4*)(gA + kt0 + j*8);
            *(uint4*)(sA + j*8) = ra;
            sp += b2f(ra.x & 0xffffu) + b2f(ra.x >> 16)
                + b2f(ra.y & 0xffffu) + b2f(ra.y >> 16)
                + b2f(ra.z & 0xffffu) + b2f(ra.z >> 16)
                + b2f(ra.w & 0xffffu) + b2f(ra.w >> 16);
        }
        {
            float4 rb0 = *(const float4*)(gB + (size_t)kt0 * D_);
            float4 rb1 = *(const float4*)(gB + (size_t)kt0 * D_ + 4);
            unsigned short vals[8];
            vals[0] = f2b(rb0.x); vals[1] = f2b(rb0.y);
            vals[2] = f2b(rb0.z); vals[3] = f2b(rb0.w);
            vals[4] = f2b(rb1.x); vals[5] = f2b(rb1.y);
            vals[6] = f2b(rb1.z); vals[7] = f2b(rb1.w);
            #pragma unroll
            for (int jj = 0; jj < 8; jj++)
                lds_bt[(dseg*8 + jj)*72 + ktr] = vals[jj];
        }
        __syncthreads();
        #pragma unroll
        for (int kk = 0; kk < 64; kk += 32){
            bf16x8 af[2], bfr[2];
            #pragma unroll
            for (int mi = 0; mi < 2; mi++)
                af[mi] = *(const bf16x8*)(lds_a + (w*32 + mi*16 + lrow)*72 + kk + quad*8);
            #pragma unroll
            for (int ni = 0; ni < 2; ni++)
                bfr[ni] = *(const bf16x8*)(lds_bt + (ni*16 + lrow)*72 + kk + quad*8);
            #pragma unroll
            for (int mi = 0; mi < 2; mi++)
                #pragma unroll
                for (int ni = 0; ni < 2; ni++)
                    acc[mi][ni] = __builtin_amdgcn_mfma_f32_16x16x32_bf16(af[mi], bfr[ni], acc[mi][ni], 0, 0, 0);
        }
        __syncthreads();
    }

    red[tid] = sp; __syncthreads();
    if (tid < 128) winv[tid] = 1.0f / ((red[2*tid] + red[2*tid+1]) + 1e-6f);
    __syncthreads();

    #pragma unroll
    for (int mi = 0; mi < 2; mi++){
        int e0 = w*32 + mi*16 + quad*4;
        #pragma unroll
        for (int ni = 0; ni < 2; ni++){
            int d = d0 + ni*16 + lrow;
            #pragma unroll
            for (int rr = 0; rr < 4; rr++){
                int e = e0 + rr;
                if (e < E_)
                    out_feat[((size_t)by*E_ + e)*D_ + d] = acc[mi][ni][rr] * winv[e];
            }
        }
    }
}

extern "C" void kernel_launch(void* const* d_in, const int* in_sizes, int n_in,
                              void* d_out, int out_size, void* d_ws, size_t ws_size,
                              hipStream_t stream){
    const float* tokens = (const float*)d_in[0];
    const float* cent   = (const float*)d_in[1];
    float* out        = (float*)d_out;
    float* out_assign = out;
    float* out_feat   = out + (size_t)B_*T_*E_;

    unsigned short* cn = (unsigned short*)d_ws;            // EP_*D_ bf16
    unsigned short* pT = cn + (size_t)EP_*D_;              // B_*EP_*T_ bf16

    k_cnorm<<<EP_, 256, 0, stream>>>(cent, cn);
    k_sim<<<NTOK/128, 256, 0, stream>>>(tokens, cn, out_assign, pT);
    k_feat<<<dim3(32, B_), 256, 0, stream>>>(tokens, pT, out_feat);
}

// Round 3
// 268.574 us; speedup vs baseline: 1.1466x; 1.1466x over previous
//
#include <hip/hip_runtime.h>

#define B_   8
#define T_   4096
#define D_   1024
#define E_   100
#define EP_  128
#define NTOK (B_*T_)

typedef short bf16x8 __attribute__((ext_vector_type(8)));
typedef float f32x4  __attribute__((ext_vector_type(4)));

__device__ __forceinline__ float b2f(unsigned int u){
    union { unsigned int i; float f; } v; v.i = u << 16; return v.f;
}
__device__ __forceinline__ unsigned short f2b(float f){
    union { float f; unsigned int i; } v; v.f = f;
    unsigned int x = v.i;
    return (unsigned short)((x + 0x7fffu + ((x >> 16) & 1u)) >> 16);
}

// ---------------- K1: normalize centroids (fp32 in) -> cn[EP_][D_] bf16 --------
__global__ __launch_bounds__(256) void k_cnorm(const float* __restrict__ cent,
                                               unsigned short* __restrict__ cn){
    const int e = blockIdx.x, tid = threadIdx.x;
    if (e >= E_){
        ((uint2*)(cn + (size_t)e*D_))[tid] = make_uint2(0u, 0u);
        return;
    }
    float4 x = ((const float4*)(cent + (size_t)e*D_))[tid];
    float ss = x.x*x.x + x.y*x.y + x.z*x.z + x.w*x.w;
    __shared__ float red[256];
    red[tid] = ss; __syncthreads();
    for (int s = 128; s > 0; s >>= 1){ if (tid < s) red[tid] += red[tid+s]; __syncthreads(); }
    float inv = 1.0f / fmaxf(sqrtf(red[0]), 1e-12f);
    unsigned int lo = (unsigned int)f2b(x.x*inv) | ((unsigned int)f2b(x.y*inv) << 16);
    unsigned int hi = (unsigned int)f2b(x.z*inv) | ((unsigned int)f2b(x.w*inv) << 16);
    ((uint2*)(cn + (size_t)e*D_))[tid] = make_uint2(lo, hi);
}

// ---------------- K2: sim GEMM + register softmax + weight atomics -------------
// grid = NTOK/64 = 512 blocks, 256 threads. Tile: 64 tokens x 128 entities.
__global__ __launch_bounds__(256) void k_sim(const float* __restrict__ tokens,
                                             const unsigned short* __restrict__ cn,
                                             float* __restrict__ out_assign,
                                             unsigned short* __restrict__ pT,
                                             float* __restrict__ wacc){
    const int tid = threadIdx.x;
    const int t0  = blockIdx.x * 64;
    const int bb  = t0 >> 12;
    const int tl0 = t0 & (T_ - 1);

    __shared__ __align__(16) unsigned short lds_a[64*72];
    __shared__ __align__(16) unsigned short lds_b[128*72];
    __shared__ float red[256];
    __shared__ float srow[64];
    __shared__ float cm[64][2];
    __shared__ float cs[64][2];

    const int r  = tid >> 2, seg  = tid & 3;     // A: 64 rows x 16 f32
    const int r2 = tid >> 1, seg2 = tid & 1;     // B: 128 rows x 32 bf16
    const float*          gA = tokens + (size_t)(t0 + r)*D_ + seg*16;
    const unsigned short* gB = cn     + (size_t)r2*D_       + seg2*32;
    unsigned short* sA = lds_a + r*72  + seg*16;
    unsigned short* sB = lds_b + r2*72 + seg2*32;

    const int lane = tid & 63, w = tid >> 6;
    const int wm = w >> 1, wn = w & 1, lrow = lane & 15, quad = lane >> 4;

    f32x4 acc[2][4];
    #pragma unroll
    for (int i = 0; i < 2; i++)
        #pragma unroll
        for (int j = 0; j < 4; j++) acc[i][j] = (f32x4){0.f,0.f,0.f,0.f};

    float ss = 0.f;

    for (int ki = 0; ki < 16; ki++){
        const int k0 = ki * 64;
        #pragma unroll
        for (int j = 0; j < 4; j++){
            float4 ra = *(const float4*)(gA + k0 + j*4);
            ss += ra.x*ra.x + ra.y*ra.y + ra.z*ra.z + ra.w*ra.w;
            unsigned int lo = (unsigned int)f2b(ra.x) | ((unsigned int)f2b(ra.y) << 16);
            unsigned int hi = (unsigned int)f2b(ra.z) | ((unsigned int)f2b(ra.w) << 16);
            *(uint2*)(sA + j*4) = make_uint2(lo, hi);
        }
        #pragma unroll
        for (int j = 0; j < 4; j++)
            *(uint4*)(sB + j*8) = *(const uint4*)(gB + k0 + j*8);
        __syncthreads();
        #pragma unroll
        for (int kk = 0; kk < 64; kk += 32){
            bf16x8 af[2], bfr[4];
            #pragma unroll
            for (int mi = 0; mi < 2; mi++)
                af[mi] = *(const bf16x8*)(lds_a + (wm*32 + mi*16 + lrow)*72 + kk + quad*8);
            #pragma unroll
            for (int ni = 0; ni < 4; ni++)
                bfr[ni] = *(const bf16x8*)(lds_b + (wn*64 + ni*16 + lrow)*72 + kk + quad*8);
            #pragma unroll
            for (int mi = 0; mi < 2; mi++)
                #pragma unroll
                for (int ni = 0; ni < 4; ni++)
                    acc[mi][ni] = __builtin_amdgcn_mfma_f32_16x16x32_bf16(af[mi], bfr[ni], acc[mi][ni], 0, 0, 0);
        }
        __syncthreads();
    }

    // token norms: 4 partials per row
    red[tid] = ss; __syncthreads();
    if (tid < 64){
        float tot = red[4*tid] + red[4*tid+1] + red[4*tid+2] + red[4*tid+3];
        srow[tid] = 10.0f / fmaxf(sqrtf(tot), 1e-12f);  // 1/(max(||x||,eps)*TEMP)
    }
    __syncthreads();

    // scale in-place; per-row max+sum in registers
    float rm[2][4], rs[2][4];
    #pragma unroll
    for (int mi = 0; mi < 2; mi++){
        #pragma unroll
        for (int rr = 0; rr < 4; rr++){
            int row = wm*32 + mi*16 + quad*4 + rr;
            float sc = srow[row];
            float m = -1e30f;
            #pragma unroll
            for (int ni = 0; ni < 4; ni++){
                int col = wn*64 + ni*16 + lrow;
                float v = acc[mi][ni][rr] * sc;
                acc[mi][ni][rr] = v;
                if (col < E_) m = fmaxf(m, v);
            }
            #pragma unroll
            for (int off = 1; off < 16; off <<= 1)
                m = fmaxf(m, __shfl_xor(m, off));
            float s = 0.f;
            #pragma unroll
            for (int ni = 0; ni < 4; ni++){
                int col = wn*64 + ni*16 + lrow;
                s += (col < E_) ? __expf(acc[mi][ni][rr] - m) : 0.f;
            }
            #pragma unroll
            for (int off = 1; off < 16; off <<= 1)
                s += __shfl_xor(s, off);
            rm[mi][rr] = m; rs[mi][rr] = s;
        }
    }
    // cross-warp (wn) combine
    if (lrow == 0){
        #pragma unroll
        for (int mi = 0; mi < 2; mi++)
            #pragma unroll
            for (int rr = 0; rr < 4; rr++){
                int row = wm*32 + mi*16 + quad*4 + rr;
                cm[row][wn] = rm[mi][rr];
                cs[row][wn] = rs[mi][rr];
            }
    }
    __syncthreads();

    #pragma unroll
    for (int mi = 0; mi < 2; mi++){
        float wp[4] = {0.f, 0.f, 0.f, 0.f};
        #pragma unroll
        for (int rr = 0; rr < 4; rr++){
            int row = wm*32 + mi*16 + quad*4 + rr;
            float m0 = cm[row][0], m1 = cm[row][1];
            float M  = fmaxf(m0, m1);
            float S  = cs[row][0]*__expf(m0 - M) + cs[row][1]*__expf(m1 - M);
            float rinv = 1.0f / S;
            #pragma unroll
            for (int ni = 0; ni < 4; ni++){
                int col = wn*64 + ni*16 + lrow;
                if (col < E_){
                    float p = __expf(acc[mi][ni][rr] - M) * rinv;
                    out_assign[(size_t)(t0 + row)*E_ + col] = p;
                    pT[((size_t)bb*EP_ + col)*T_ + tl0 + row] = f2b(p);
                    wp[ni] += p;
                }
            }
        }
        // weight partials: reduce over quads, one atomic per col per warp
        #pragma unroll
        for (int ni = 0; ni < 4; ni++){
            int col = wn*64 + ni*16 + lrow;
            float v = wp[ni];
            v += __shfl_xor(v, 16);
            v += __shfl_xor(v, 32);
            if (quad == 0 && col < E_)
                atomicAdd(&wacc[bb*E_ + col], v);
        }
    }
}

// ---------------- K3: partial entity_features via split-T atomics --------------
// grid = (16 d-tiles, 4 t-chunks, 8 batches), 256 threads. Tile 128e x 64d, K=1024.
__global__ __launch_bounds__(256) void k_feat(const float* __restrict__ tokens,
                                              const unsigned short* __restrict__ pT,
                                              float* __restrict__ facc){
    const int tid = threadIdx.x;
    const int d0  = blockIdx.x * 64;
    const int tc  = blockIdx.y;
    const int bb  = blockIdx.z;

    __shared__ __align__(16) unsigned short lds_a[128*72];   // [e][t] bf16
    __shared__ __align__(16) unsigned short lds_bt[64*72];   // [d][t] bf16

    const int r = tid >> 1, seg = tid & 1;
    const unsigned short* gA = pT + ((size_t)bb*EP_ + r)*T_ + tc*1024 + seg*32;
    unsigned short* sA = lds_a + r*72 + seg*32;

    const int tr = tid >> 2, dseg = tid & 3;
    const float* gB = tokens + ((size_t)(bb*T_ + tc*1024 + tr))*D_ + d0 + dseg*16;

    const int lane = tid & 63, w = tid >> 6;
    const int wm = w >> 1, wn = w & 1, lrow = lane & 15, quad = lane >> 4;

    f32x4 acc[4][2];
    #pragma unroll
    for (int i = 0; i < 4; i++)
        #pragma unroll
        for (int j = 0; j < 2; j++) acc[i][j] = (f32x4){0.f,0.f,0.f,0.f};

    for (int kt0 = 0; kt0 < 1024; kt0 += 64){
        #pragma unroll
        for (int j = 0; j < 4; j++)
            *(uint4*)(sA + j*8) = *(const uint4*)(gA + kt0 + j*8);
        #pragma unroll
        for (int j = 0; j < 4; j++){
            float4 rb = *(const float4*)(gB + (size_t)kt0*D_ + j*4);
            int dloc = dseg*16 + j*4;
            lds_bt[(dloc+0)*72 + tr] = f2b(rb.x);
            lds_bt[(dloc+1)*72 + tr] = f2b(rb.y);
            lds_bt[(dloc+2)*72 + tr] = f2b(rb.z);
            lds_bt[(dloc+3)*72 + tr] = f2b(rb.w);
        }
        __syncthreads();
        #pragma unroll
        for (int kk = 0; kk < 64; kk += 32){
            bf16x8 af[4], bfr[2];
            #pragma unroll
            for (int mi = 0; mi < 4; mi++)
                af[mi] = *(const bf16x8*)(lds_a + (wm*64 + mi*16 + lrow)*72 + kk + quad*8);
            #pragma unroll
            for (int ni = 0; ni < 2; ni++)
                bfr[ni] = *(const bf16x8*)(lds_bt + (wn*32 + ni*16 + lrow)*72 + kk + quad*8);
            #pragma unroll
            for (int mi = 0; mi < 4; mi++)
                #pragma unroll
                for (int ni = 0; ni < 2; ni++)
                    acc[mi][ni] = __builtin_amdgcn_mfma_f32_16x16x32_bf16(af[mi], bfr[ni], acc[mi][ni], 0, 0, 0);
        }
        __syncthreads();
    }

    #pragma unroll
    for (int mi = 0; mi < 4; mi++){
        #pragma unroll
        for (int ni = 0; ni < 2; ni++){
            int d = d0 + wn*32 + ni*16 + lrow;
            #pragma unroll
            for (int rr = 0; rr < 4; rr++){
                int e = wm*64 + mi*16 + quad*4 + rr;
                if (e < E_)
                    atomicAdd(&facc[((size_t)bb*E_ + e)*D_ + d], acc[mi][ni][rr]);
            }
        }
    }
}

// ---------------- K4: out_feat = facc / (wacc + eps) ---------------------------
__global__ __launch_bounds__(256) void k_final(const float* __restrict__ facc,
                                               const float* __restrict__ wacc,
                                               float* __restrict__ out_feat){
    const int idx = blockIdx.x * 256 + threadIdx.x;   // 204800 threads x 4 floats
    const int base = idx * 4;
    const int be = base >> 10;
    float4 v = *(const float4*)(facc + base);
    float winv = 1.0f / (wacc[be] + 1e-6f);
    v.x *= winv; v.y *= winv; v.z *= winv; v.w *= winv;
    *(float4*)(out_feat + base) = v;
}

extern "C" void kernel_launch(void* const* d_in, const int* in_sizes, int n_in,
                              void* d_out, int out_size, void* d_ws, size_t ws_size,
                              hipStream_t stream){
    const float* tokens = (const float*)d_in[0];
    const float* cent   = (const float*)d_in[1];
    float* out        = (float*)d_out;
    float* out_assign = out;
    float* out_feat   = out + (size_t)B_*T_*E_;

    float* facc = (float*)d_ws;                              // B*E*D fp32
    float* wacc = facc + (size_t)B_*E_*D_;                   // B*E fp32
    unsigned short* cn = (unsigned short*)(wacc + B_*E_);    // EP_*D_ bf16
    unsigned short* pT = cn + (size_t)EP_*D_;                // B_*EP_*T_ bf16

    hipMemsetAsync(d_ws, 0, ((size_t)B_*E_*D_ + B_*E_)*sizeof(float), stream);
    k_cnorm<<<EP_, 256, 0, stream>>>(cent, cn);
    k_sim<<<NTOK/64, 256, 0, stream>>>(tokens, cn, out_assign, pT, wacc);
    k_feat<<<dim3(16, 4, B_), 256, 0, stream>>>(tokens, pT, facc);
    k_final<<<(B_*E_*D_)/1024, 256, 0, stream>>>(facc, wacc, out_feat);
}